// Round 18
// baseline (73.093 us; speedup 1.0000x reference)
//
#include <hip/hip_runtime.h>
#include <cmath>
#include <complex>
#include <cstring>
#include <algorithm>

#define DIM_IN  288
#define DIM_SHD 9
#define NB      10
#define NH      16
#define EPB     16
#define BLOCK   256
#define NINSTR  11
#define XSTR    292
#define ZG_STRIDE 116       // per-wave z row stride (floats): 14 slots x 8u + pad, 16B-aligned
#define ZG_SIZE  (16 * ZG_STRIDE)   // 1856 fl per wave
#define W2B_ELEMS (NINSTR * 32 * 32 * 32)   // [ins][u][w][t0..31]; t=16 holds b2, t>16 zero

// LDS pool (floats), total 7616 fl = 30464 B -> 5 blocks/CU at VGPR<=102:
//   s_zw : [0, 7424)   4 waves x 1856, PRIVATE per-wave group-z
//   s_sh : [7424, 7616)
//   s_basis: alias wave-2 z (160 fl; dead before main loop, barrier-protected)
//   s_hb   : alias wave-3 z (512 ushort; dead before main loop, barrier-protected)
//   out-gather: alias s_zw[0..4672) between passes (z dead, barrier-protected)
#define OFF_SH 7424
#define POOLSZ 7616

typedef __attribute__((ext_vector_type(8))) short  short8b;
typedef __attribute__((ext_vector_type(4))) float  f32x4;
typedef __attribute__((ext_vector_type(2))) float  f32x2;

__device__ float g_C[NINSTR][125];

__device__ __forceinline__ unsigned short f2bf(float f) {
  unsigned int u = __float_as_uint(f);
  unsigned int r = (u + 0x7fffu + ((u >> 16) & 1u)) >> 16;   // RNE
  return (unsigned short)r;
}

// W2 -> bf16 [ins][u][w][t]; t<16 = W2 row t, t==16 = b2 (hB carries 1.0 there), t>16 = 0
__global__ __launch_bounds__(256) void prep_w2(const float* __restrict__ W2,
                                               const float* __restrict__ b2,
                                               unsigned short* __restrict__ W2b) {
  int gid = blockIdx.x * 256 + threadIdx.x;
  if (gid < W2B_ELEMS) {
    int c = gid >> 5, t = gid & 31;          // c = ins*1024 + u*32 + w
    float v = (t < 16) ? W2[(size_t)t * 11264 + c] : (t == 16 ? b2[c] : 0.0f);
    W2b[gid] = f2bf(v);
  }
}

// ---- one instruction's z from in-register x, pk-fma packed ----
template<int INS,int D1,int D2,int D3,int OFF2,int SLOT>
__device__ __forceinline__ void z_one(const float (&xv)[D1],
                                      const float* __restrict__ she,
                                      float* __restrict__ zo)
{
  const float* __restrict__ Cp = g_C[INS];
  constexpr int NP = D3 / 2;              // D3 odd: 1,3,5 -> 0,1,2 pairs
  f32x2 zk2[NP > 0 ? NP : 1];
  float zkl = 0.f;
  #pragma unroll
  for (int m = 0; m < NP; ++m) zk2[m] = (f32x2){0.f, 0.f};
  #pragma unroll
  for (int i = 0; i < D1; ++i) {
    #pragma unroll
    for (int j = 0; j < D2; ++j) {
      float pr = xv[i] * she[OFF2 + j];
      f32x2 pr2 = {pr, pr};
      const float* cb = Cp + (i * D2 + j) * D3;
      #pragma unroll
      for (int m = 0; m < NP; ++m) {
        f32x2 cc = {cb[2 * m], cb[2 * m + 1]};
        zk2[m] = __builtin_elementwise_fma(cc, pr2, zk2[m]);
      }
      zkl = fmaf(cb[D3 - 1], pr, zkl);
    }
  }
  #pragma unroll
  for (int m = 0; m < NP; ++m) {
    zo[(SLOT + 2 * m) * 8]     = zk2[m].x;
    zo[(SLOT + 2 * m + 1) * 8] = zk2[m].y;
  }
  zo[(SLOT + D3 - 1) * 8] = zkl;
}

// ---- per-WAVE group z-phases: 16e x 8u tasks over 64 lanes, x from GLOBAL ----
template<int D1,int OFF1>
__device__ __forceinline__ void load_x(const float* __restrict__ xg, int e0,
                                       int e, int u, float (&xv)[D1]) {
  const float* xp = xg + (size_t)(e0 + e) * DIM_IN + OFF1 + u * D1;
  #pragma unroll
  for (int i = 0; i < D1; ++i) xv[i] = xp[i];
}

__device__ __forceinline__ void z_group_l0(int lane, int q, int e0,
    const float* __restrict__ xg, const float* __restrict__ s_sh,
    float* __restrict__ zw) {
  #pragma unroll
  for (int s = 0; s < 2; ++s) {
    int id = lane + s * 64;
    int e = id >> 3, ul = id & 7, u = q * 8 + ul;
    float xv[1];
    load_x<1, 0>(xg, e0, e, u, xv);
    const float* she = s_sh + e * 12;
    float* zo = zw + e * ZG_STRIDE + ul;
    z_one<0, 1, 1, 1, 0, 0>(xv, she, zo);
    z_one<1, 1, 3, 3, 1, 1>(xv, she, zo);
    z_one<2, 1, 5, 5, 4, 4>(xv, she, zo);
  }
}

__device__ __forceinline__ void z_group_l1(int lane, int q, int e0,
    const float* __restrict__ xg, const float* __restrict__ s_sh,
    float* __restrict__ zw) {
  #pragma unroll
  for (int s = 0; s < 2; ++s) {
    int id = lane + s * 64;
    int e = id >> 3, ul = id & 7, u = q * 8 + ul;
    float xv[3];
    load_x<3, 32>(xg, e0, e, u, xv);
    const float* she = s_sh + e * 12;
    float* zo = zw + e * ZG_STRIDE + ul;
    z_one<3, 3, 1, 3, 0, 0>(xv, she, zo);
    z_one<4, 3, 3, 1, 1, 3>(xv, she, zo);
    z_one<5, 3, 3, 5, 1, 4>(xv, she, zo);
    z_one<6, 3, 5, 3, 4, 9>(xv, she, zo);
  }
}

__device__ __forceinline__ void z_group_l2(int lane, int q, int e0,
    const float* __restrict__ xg, const float* __restrict__ s_sh,
    float* __restrict__ zw) {
  #pragma unroll
  for (int s = 0; s < 2; ++s) {
    int id = lane + s * 64;
    int e = id >> 3, ul = id & 7, u = q * 8 + ul;
    float xv[5];
    load_x<5, 128>(xg, e0, e, u, xv);
    const float* she = s_sh + e * 12;
    float* zo = zw + e * ZG_STRIDE + ul;
    z_one< 7, 5, 1, 5, 0, 0>(xv, she, zo);
    z_one< 8, 5, 3, 3, 1, 5>(xv, she, zo);
    z_one< 9, 5, 5, 1, 4, 8>(xv, she, zo);
    z_one<10, 5, 5, 5, 4, 9>(xv, she, zo);
  }
}

// ---- MFMA weight-gen (bias folded via t=16) + pk-fma u-contraction ----
// single w-tile (WT) per pass: acc = 2 reg-pairs x 9 slots = 36 VGPR
template<int INS,int D3,int SB,int SLOT,int WT>
__device__ __forceinline__ void contract_h(
    int ls, int lq, int q,
    const unsigned short* __restrict__ W2b,
    const float* __restrict__ zw, short8b hB, f32x2 (&acc)[2][9])
{
  const unsigned short* Ap =
      W2b + ((size_t)(INS * 32 + q * 8) * 32 + ls) * 32 + lq * 8 + WT * 512;
  const float* zb = zw + ls * ZG_STRIDE + SLOT * 8;
  const f32x4 zero4 = {0.f, 0.f, 0.f, 0.f};

  short8b Rc = *(const short8b*)(Ap);
  short8b Rn = *(const short8b*)(Ap + 1024);
  f32x4 w_cur = __builtin_amdgcn_mfma_f32_16x16x32_bf16(Rc, hB, zero4, 0, 0, 0);

  #pragma unroll
  for (int c = 0; c < 2; ++c) {
    float4 zq[D3];
    #pragma unroll
    for (int k = 0; k < D3; ++k)
      zq[k] = *(const float4*)(zb + k * 8 + c * 4);    // 2-way banks, free
    #pragma unroll
    for (int i = 0; i < 4; ++i) {
      const int g = c * 4 + i;              // ul (0..7)
      f32x4 w_next;
      if (g < 7) {
        w_next = __builtin_amdgcn_mfma_f32_16x16x32_bf16(Rn, hB, zero4, 0, 0, 0);
        if (g + 2 < 8) Rn = *(const short8b*)(Ap + (size_t)(g + 2) * 1024);
      }
      f32x2 wlo = {w_cur[0], w_cur[1]};
      f32x2 whi = {w_cur[2], w_cur[3]};
      #pragma unroll
      for (int k = 0; k < D3; ++k) {
        const float zz = (i == 0) ? zq[k].x : (i == 1) ? zq[k].y
                       : (i == 2) ? zq[k].z : zq[k].w;
        f32x2 zv = {zz, zz};
        acc[0][SB + k] = __builtin_elementwise_fma(wlo, zv, acc[0][SB + k]);
        acc[1][SB + k] = __builtin_elementwise_fma(whi, zv, acc[1][SB + k]);
      }
      if (g < 7) w_cur = w_next;
    }
  }
}

// ---- one full pass: z-groups + contracts for w-tile WT, then reduce+store ----
template<int WT>
__device__ __forceinline__ void run_pass(
    int tid, int lane, int ls, int lq, int q, int e0,
    const float* __restrict__ xg, const float* __restrict__ s_sh,
    float* __restrict__ zw, float* __restrict__ s_pool,
    const unsigned short* __restrict__ W2b, short8b hB,
    float* __restrict__ out)
{
  f32x2 acc[2][9];
  #pragma unroll
  for (int p = 0; p < 2; ++p)
    #pragma unroll
    for (int a = 0; a < 9; ++a) acc[p][a] = (f32x2){0.f, 0.f};

  z_group_l0(lane, q, e0, xg, s_sh, zw);
  contract_h< 0, 1, 0, 0, WT>(ls, lq, q, W2b, zw, hB, acc);
  contract_h< 1, 3, 1, 1, WT>(ls, lq, q, W2b, zw, hB, acc);
  contract_h< 2, 5, 4, 4, WT>(ls, lq, q, W2b, zw, hB, acc);

  z_group_l1(lane, q, e0, xg, s_sh, zw);
  contract_h< 3, 3, 1, 0, WT>(ls, lq, q, W2b, zw, hB, acc);
  contract_h< 4, 1, 0, 3, WT>(ls, lq, q, W2b, zw, hB, acc);
  contract_h< 5, 5, 4, 4, WT>(ls, lq, q, W2b, zw, hB, acc);
  contract_h< 6, 3, 1, 9, WT>(ls, lq, q, W2b, zw, hB, acc);

  z_group_l2(lane, q, e0, xg, s_sh, zw);
  contract_h< 7, 5, 4, 0, WT>(ls, lq, q, W2b, zw, hB, acc);
  contract_h< 8, 3, 1, 5, WT>(ls, lq, q, W2b, zw, hB, acc);
  contract_h< 9, 1, 0, 8, WT>(ls, lq, q, W2b, zw, hB, acc);
  contract_h<10, 5, 4, 9, WT>(ls, lq, q, W2b, zw, hB, acc);

  // ---- epilogue: 4-phase u-quarter reduction into pool (z dead), store ----
  __syncthreads();
  float* s_og = s_pool;            // stride XSTR=292, 4672 fl <= z region
  #pragma unroll
  for (int ph = 3; ph >= 0; --ph) {
    if (q == ph) {
      float* row = s_og + ls * XSTR;
      #pragma unroll
      for (int r = 0; r < 4; ++r) {
        const int w = WT * 16 + lq * 4 + r;
        float vals[9];
        #pragma unroll
        for (int a = 0; a < 9; ++a)
          vals[a] = (r & 1) ? acc[r >> 1][a].y : acc[r >> 1][a].x;
        if (ph == 3) {
          row[w] = vals[0];
          #pragma unroll
          for (int k = 0; k < 3; ++k) row[32 + w * 3 + k] = vals[1 + k];
          #pragma unroll
          for (int k = 0; k < 5; ++k) row[128 + w * 5 + k] = vals[4 + k];
        } else {
          row[w] += vals[0];
          #pragma unroll
          for (int k = 0; k < 3; ++k) row[32 + w * 3 + k] += vals[1 + k];
          #pragma unroll
          for (int k = 0; k < 5; ++k) row[128 + w * 5 + k] += vals[4 + k];
        }
      }
    }
    __syncthreads();
  }
  // coalesced store of this w-tile's column slices: 16 e x 36 float4
  for (int i4 = tid; i4 < EPB * 36; i4 += BLOCK) {
    int e = i4 / 36, r = i4 - e * 36;
    int col = (r < 4)  ? (WT * 16 + r * 4)
            : (r < 16) ? (32 + WT * 48 + (r - 4) * 4)
                       : (128 + WT * 80 + (r - 16) * 4);
    float4 v = *(const float4*)(s_og + e * XSTR + col);
    *(float4*)(out + (size_t)(e0 + e) * DIM_IN + col) = v;
  }
  __syncthreads();   // s_og reads done before next pass's z overwrites it
}

// NOTE (journal): VGPR cap = 256 / (2nd launch_bounds arg) on this hipcc.
// r13/r17 (group-z, zero-barrier, 4 waves x 8u, pk-fma, acc=72reg): 68.2/68.3us.
// TLP/ILP surface: 8w@VGPR60=71.7 (r11, barriered), 4w@124=68.2, 2w@252=109.
// r18: acc halved via two wt-passes (z recomputed) -> target VGPR<=102 ->
// 5 blocks/CU (LDS-limited) — the untested 5-waves/SIMD point on r13 structure.
__global__ __launch_bounds__(BLOCK, 2) void conv_kernel(
    const float* __restrict__ xg, const float* __restrict__ shg,
    const float* __restrict__ dist, const float* __restrict__ freq,
    const float* __restrict__ W1, const float* __restrict__ b1,
    const unsigned short* __restrict__ W2b,
    float* __restrict__ out)
{
  __shared__ float s_pool[POOLSZ];        // 30464 B
  float* s_sh = s_pool + OFF_SH;

  const int tid = threadIdx.x;
  const int e0 = blockIdx.x * EPB;
  const int lane = tid & 63;
  const int ls = lane & 15;       // e-col (B/C cols) & w-row selector (A rows)
  const int lq = lane >> 4;       // 0..3 k-slice / output reg quad
  const int q   = tid >> 6;       // 0..3 u-quarter (wave id)
  float* zw = s_pool + q * ZG_SIZE;                        // private group-z
  float* s_basis = s_pool + 2 * ZG_SIZE;                   // alias wave-2 z
  unsigned short* s_hb = (unsigned short*)(s_pool + 3 * ZG_SIZE); // alias wave-3 z

  // ---- prologue A: sh + radial basis ----
  if (tid < EPB * DIM_SHD) {
    int e = tid / DIM_SHD, c = tid - (tid / DIM_SHD) * DIM_SHD;
    s_sh[e * 12 + c] = shg[(size_t)(e0 + e) * DIM_SHD + c];
  }
  if (tid < EPB * NB) {
    int e = tid / NB, n = tid - (tid / NB) * NB;
    float d  = dist[e0 + e];
    float xv = d * 0.25f;
    float x2 = xv * xv, x4 = x2 * x2, x5 = x4 * xv;
    float env = 1.0f / xv + x5 * fmaf(xv, fmaf(xv, -21.0f, 48.0f), -28.0f);
    env = (xv < 1.0f) ? env : 0.0f;
    s_basis[e * NB + n] = env * sinf(freq[n] * xv);
  }
  __syncthreads();

  // ---- prologue B: radial MLP hidden layer (256 tasks) ----
  {
    int e = tid >> 4, t = tid & 15;
    float v = b1[t];
    #pragma unroll
    for (int n = 0; n < NB; ++n) v = fmaf(s_basis[e * NB + n], W1[n * NH + t], v);
    v = v / (1.0f + expf(-v));          // silu
    s_hb[e * 32 + t] = f2bf(v);
    s_hb[e * 32 + t + 16] = (t == 0) ? (unsigned short)0x3F80 : (unsigned short)0;
  }
  __syncthreads();
  short8b hB = *(const short8b*)(s_hb + ls * 32 + lq * 8);
  __syncthreads();   // all waves hold hB before waves 2/3 overwrite aliased buffers

  run_pass<0>(tid, lane, ls, lq, q, e0, xg, s_sh, zw, s_pool, W2b, hB, out);
  run_pass<1>(tid, lane, ls, lq, q, e0, xg, s_sh, zw, s_pool, W2b, hB, out);
}

// ===================== host-side Wigner-3j (mirrors reference) =====================
typedef std::complex<double> cd;

static double factd(int n) { double r = 1; for (int i = 2; i <= n; ++i) r *= i; return r; }

static double su2_cg(int j1, int j2, int j3, int m1, int m2, int m3) {
  if (m3 != m1 + m2) return 0.0;
  int vmin = std::max(std::max(-j1 + j2 + m3, -j1 + m1), 0);
  int vmax = std::min(std::min(j2 + j3 + m1, j3 - j1 + j2), j3 + m3);
  if (vmax < vmin) return 0.0;
  double c = std::sqrt(
      factd(2*j3+1) * factd(j3+j1-j2) * factd(j3-j1+j2) * factd(j1+j2-j3) / factd(j1+j2+j3+1)
      * factd(j3+m3) * factd(j3-m3)
      / (factd(j1+m1) * factd(j1-m1) * factd(j2+m2) * factd(j2-m2)));
  double s = 0.0;
  for (int v = vmin; v <= vmax; ++v) {
    double sg = ((v + j2 + m2) & 1) ? -1.0 : 1.0;
    s += sg * factd(j2+j3+m1-v) * factd(j1-m1+v)
         / (factd(v) * factd(j3-j1+j2-v) * factd(j3+m3-v) * factd(v+j1-j2-m3));
  }
  return c * s;
}

static void qmat(int l, cd q[5][5]) {
  for (int a = 0; a < 5; ++a) for (int b = 0; b < 5; ++b) q[a][b] = cd(0, 0);
  const double s = 1.0 / std::sqrt(2.0);
  for (int m = -l; m < 0; ++m) {
    q[l + m][l - m] = cd(s, 0);
    q[l + m][l + m] = cd(0, -s);
  }
  q[l][l] = cd(1, 0);
  for (int m = 1; m <= l; ++m) {
    double sg = (m & 1) ? -1.0 : 1.0;
    q[l + m][l + m] = cd(sg * s, 0);
    q[l + m][l - m] = cd(0, sg * s);
  }
  cd ph = (l == 0) ? cd(1, 0) : (l == 1) ? cd(0, -1) : cd(-1, 0);  // (-i)^l
  for (int a = 0; a < 5; ++a) for (int b = 0; b < 5; ++b) q[a][b] *= ph;
}

static void wigner3j(int l1, int l2, int l3, double C[5][5][5]) {
  int d1 = 2*l1+1, d2 = 2*l2+1, d3 = 2*l3+1;
  cd q1[5][5], q2[5][5], q3[5][5];
  qmat(l1, q1); qmat(l2, q2); qmat(l3, q3);
  double norm2 = 0;
  for (int j = 0; j < d1; ++j)
    for (int l = 0; l < d2; ++l)
      for (int n = 0; n < d3; ++n) {
        cd sum(0, 0);
        for (int i = 0; i < d1; ++i)
          for (int k = 0; k < d2; ++k)
            for (int m = 0; m < d3; ++m) {
              double cg = su2_cg(l1, l2, l3, i - l1, k - l2, m - l3);
              if (cg != 0.0) sum += q1[i][j] * q2[k][l] * std::conj(q3[m][n]) * cg;
            }
        C[j][l][n] = sum.real();
        norm2 += C[j][l][n] * C[j][l][n];
      }
  double nrm = std::sqrt(norm2);
  if (nrm > 0)
    for (int j = 0; j < d1; ++j)
      for (int l = 0; l < d2; ++l)
        for (int n = 0; n < d3; ++n) C[j][l][n] /= nrm;
}

static void build_C_host(float C_out[NINSTR][125]) {
  const int L1[NINSTR] = {0,0,0,1,1,1,1,2,2,2,2};
  const int L2[NINSTR] = {0,1,2,0,1,1,2,0,1,2,2};
  const int L3[NINSTR] = {0,1,2,1,0,2,1,2,1,0,2};
  std::memset(C_out, 0, sizeof(float) * NINSTR * 125);
  for (int ins = 0; ins < NINSTR; ++ins) {
    int l1 = L1[ins], l2 = L2[ins], l3 = L3[ins];
    int d1 = 2*l1+1, d2 = 2*l2+1, d3 = 2*l3+1;
    double C[5][5][5];
    wigner3j(l1, l2, l3, C);
    double fan = (l3 == 0) ? 96.0 : 128.0;
    double pw = std::sqrt((2*l3+1) / fan);
    for (int i = 0; i < d1; ++i)
      for (int j = 0; j < d2; ++j)
        for (int k = 0; k < d3; ++k)
          C_out[ins][(i * d2 + j) * d3 + k] = (float)(pw * C[i][j][k]);
  }
}

extern "C" void kernel_launch(void* const* d_in, const int* in_sizes, int n_in,
                              void* d_out, int out_size, void* d_ws, size_t ws_size,
                              hipStream_t stream) {
  static float hC[NINSTR][125];
  build_C_host(hC);
  void* dC = nullptr;
  hipGetSymbolAddress(&dC, HIP_SYMBOL(g_C));
  hipMemcpyAsync(dC, hC, sizeof(hC), hipMemcpyHostToDevice, stream);

  const float* xg   = (const float*)d_in[0];
  const float* shg  = (const float*)d_in[1];
  const float* dist = (const float*)d_in[2];
  const float* freq = (const float*)d_in[3];
  const float* W1   = (const float*)d_in[4];
  const float* b1   = (const float*)d_in[5];
  const float* W2   = (const float*)d_in[6];
  const float* b2   = (const float*)d_in[7];
  float* out = (float*)d_out;
  unsigned short* W2b = (unsigned short*)d_ws;    // 720896 bytes

  prep_w2<<<(W2B_ELEMS + 255) / 256, 256, 0, stream>>>(W2, b2, W2b);

  int E = in_sizes[2];            // 16384
  int blocks = E / EPB;           // 1024
  conv_kernel<<<blocks, BLOCK, 0, stream>>>(xg, shg, dist, freq, W1, b1, W2b, out);
}

// Round 19
// 68.058 us; speedup vs baseline: 1.0740x; 1.0740x over previous
//
#include <hip/hip_runtime.h>
#include <cmath>
#include <complex>
#include <cstring>
#include <algorithm>

#define DIM_IN  288
#define DIM_SHD 9
#define NB      10
#define NH      16
#define EPB     16
#define BLOCK   256
#define NINSTR  11
#define XSTR    292
#define ZG_STRIDE 116       // per-wave z row stride (floats): 14 slots x 8u + pad, 16B-aligned
#define ZG_SIZE  (16 * ZG_STRIDE)   // 1856 fl per wave
#define W2B_ELEMS (NINSTR * 32 * 32 * 32)   // [ins][u][w][t0..31]; t=16 holds b2, t>16 zero

// LDS pool (floats), total 7616 fl = 30464 B:
//   s_zw : [0, 7424)   4 waves x 1856, PRIVATE per-wave group-z
//   s_sh : [7424, 7616)
//   s_basis: alias wave-2 z (160 fl; dead before main loop, barrier-protected)
//   s_hb   : alias wave-3 z (512 ushort; dead before main loop, barrier-protected)
//   out-gather: alias s_zw[0..4672) (all z dead, barrier-protected), stride 292
#define OFF_SH 7424
#define POOLSZ 7616

typedef __attribute__((ext_vector_type(8))) short  short8b;
typedef __attribute__((ext_vector_type(4))) float  f32x4;
typedef __attribute__((ext_vector_type(2))) float  f32x2;

__device__ float g_C[NINSTR][125];

__device__ __forceinline__ unsigned short f2bf(float f) {
  unsigned int u = __float_as_uint(f);
  unsigned int r = (u + 0x7fffu + ((u >> 16) & 1u)) >> 16;   // RNE
  return (unsigned short)r;
}

// W2 -> bf16 [ins][u][w][t]; t<16 = W2 row t, t==16 = b2 (hB carries 1.0 there), t>16 = 0
__global__ __launch_bounds__(256) void prep_w2(const float* __restrict__ W2,
                                               const float* __restrict__ b2,
                                               unsigned short* __restrict__ W2b) {
  int gid = blockIdx.x * 256 + threadIdx.x;
  if (gid < W2B_ELEMS) {
    int c = gid >> 5, t = gid & 31;          // c = ins*1024 + u*32 + w
    float v = (t < 16) ? W2[(size_t)t * 11264 + c] : (t == 16 ? b2[c] : 0.0f);
    W2b[gid] = f2bf(v);
  }
}

// ---- one instruction's z from in-register x, pk-fma packed ----
template<int INS,int D1,int D2,int D3,int OFF2,int SLOT>
__device__ __forceinline__ void z_one(const float (&xv)[D1],
                                      const float* __restrict__ she,
                                      float* __restrict__ zo)
{
  const float* __restrict__ Cp = g_C[INS];
  constexpr int NP = D3 / 2;              // D3 odd: 1,3,5 -> 0,1,2 pairs
  f32x2 zk2[NP > 0 ? NP : 1];
  float zkl = 0.f;
  #pragma unroll
  for (int m = 0; m < NP; ++m) zk2[m] = (f32x2){0.f, 0.f};
  #pragma unroll
  for (int i = 0; i < D1; ++i) {
    #pragma unroll
    for (int j = 0; j < D2; ++j) {
      float pr = xv[i] * she[OFF2 + j];
      f32x2 pr2 = {pr, pr};
      const float* cb = Cp + (i * D2 + j) * D3;
      #pragma unroll
      for (int m = 0; m < NP; ++m) {
        f32x2 cc = {cb[2 * m], cb[2 * m + 1]};
        zk2[m] = __builtin_elementwise_fma(cc, pr2, zk2[m]);
      }
      zkl = fmaf(cb[D3 - 1], pr, zkl);
    }
  }
  #pragma unroll
  for (int m = 0; m < NP; ++m) {
    zo[(SLOT + 2 * m) * 8]     = zk2[m].x;
    zo[(SLOT + 2 * m + 1) * 8] = zk2[m].y;
  }
  zo[(SLOT + D3 - 1) * 8] = zkl;
}

// ---- per-WAVE group z-phases: 16e x 8u tasks over 64 lanes, x from GLOBAL ----
template<int D1,int OFF1>
__device__ __forceinline__ void load_x(const float* __restrict__ xg, int e0,
                                       int e, int u, float (&xv)[D1]) {
  const float* xp = xg + (size_t)(e0 + e) * DIM_IN + OFF1 + u * D1;
  #pragma unroll
  for (int i = 0; i < D1; ++i) xv[i] = xp[i];
}

__device__ __forceinline__ void z_group_l0(int lane, int q, int e0,
    const float* __restrict__ xg, const float* __restrict__ s_sh,
    float* __restrict__ zw) {
  #pragma unroll
  for (int s = 0; s < 2; ++s) {
    int id = lane + s * 64;
    int e = id >> 3, ul = id & 7, u = q * 8 + ul;
    float xv[1];
    load_x<1, 0>(xg, e0, e, u, xv);
    const float* she = s_sh + e * 12;
    float* zo = zw + e * ZG_STRIDE + ul;
    z_one<0, 1, 1, 1, 0, 0>(xv, she, zo);
    z_one<1, 1, 3, 3, 1, 1>(xv, she, zo);
    z_one<2, 1, 5, 5, 4, 4>(xv, she, zo);
  }
}

__device__ __forceinline__ void z_group_l1(int lane, int q, int e0,
    const float* __restrict__ xg, const float* __restrict__ s_sh,
    float* __restrict__ zw) {
  #pragma unroll
  for (int s = 0; s < 2; ++s) {
    int id = lane + s * 64;
    int e = id >> 3, ul = id & 7, u = q * 8 + ul;
    float xv[3];
    load_x<3, 32>(xg, e0, e, u, xv);
    const float* she = s_sh + e * 12;
    float* zo = zw + e * ZG_STRIDE + ul;
    z_one<3, 3, 1, 3, 0, 0>(xv, she, zo);
    z_one<4, 3, 3, 1, 1, 3>(xv, she, zo);
    z_one<5, 3, 3, 5, 1, 4>(xv, she, zo);
    z_one<6, 3, 5, 3, 4, 9>(xv, she, zo);
  }
}

__device__ __forceinline__ void z_group_l2(int lane, int q, int e0,
    const float* __restrict__ xg, const float* __restrict__ s_sh,
    float* __restrict__ zw) {
  #pragma unroll
  for (int s = 0; s < 2; ++s) {
    int id = lane + s * 64;
    int e = id >> 3, ul = id & 7, u = q * 8 + ul;
    float xv[5];
    load_x<5, 128>(xg, e0, e, u, xv);
    const float* she = s_sh + e * 12;
    float* zo = zw + e * ZG_STRIDE + ul;
    z_one< 7, 5, 1, 5, 0, 0>(xv, she, zo);
    z_one< 8, 5, 3, 3, 1, 5>(xv, she, zo);
    z_one< 9, 5, 5, 1, 4, 8>(xv, she, zo);
    z_one<10, 5, 5, 5, 4, 9>(xv, she, zo);
  }
}

// ---- MFMA weight-gen (bias folded via t=16) + pk-fma u-contraction ----
template<int INS,int D3,int SB,int SLOT>
__device__ __forceinline__ void contract_q(
    int ls, int lq, int q,
    const unsigned short* __restrict__ W2b,
    const float* __restrict__ zw, short8b hB, f32x2 (&acc)[2][2][9])
{
  const unsigned short* Ap =
      W2b + ((size_t)(INS * 32 + q * 8) * 32 + ls) * 32 + lq * 8;
  // offsets: ul*1024 (u row), wt*512 (w-tile)
  const float* zb = zw + ls * ZG_STRIDE + SLOT * 8;
  const f32x4 zero4 = {0.f, 0.f, 0.f, 0.f};

  short8b R0c = *(const short8b*)(Ap);
  short8b R1c = *(const short8b*)(Ap + 512);
  short8b R0n = *(const short8b*)(Ap + 1024);
  short8b R1n = *(const short8b*)(Ap + 1536);
  f32x4 w0_cur = __builtin_amdgcn_mfma_f32_16x16x32_bf16(R0c, hB, zero4, 0, 0, 0);
  f32x4 w1_cur = __builtin_amdgcn_mfma_f32_16x16x32_bf16(R1c, hB, zero4, 0, 0, 0);

  #pragma unroll
  for (int c = 0; c < 2; ++c) {
    float4 zq[D3];
    #pragma unroll
    for (int k = 0; k < D3; ++k)
      zq[k] = *(const float4*)(zb + k * 8 + c * 4);    // 2-way banks, free
    #pragma unroll
    for (int i = 0; i < 4; ++i) {
      const int g = c * 4 + i;              // ul (0..7)
      f32x4 w0n, w1n;
      if (g < 7) {
        w0n = __builtin_amdgcn_mfma_f32_16x16x32_bf16(R0n, hB, zero4, 0, 0, 0);
        w1n = __builtin_amdgcn_mfma_f32_16x16x32_bf16(R1n, hB, zero4, 0, 0, 0);
        if (g + 2 < 8) {
          R0n = *(const short8b*)(Ap + (size_t)(g + 2) * 1024);
          R1n = *(const short8b*)(Ap + (size_t)(g + 2) * 1024 + 512);
        }
      }
      f32x2 w0lo = {w0_cur[0], w0_cur[1]};
      f32x2 w0hi = {w0_cur[2], w0_cur[3]};
      f32x2 w1lo = {w1_cur[0], w1_cur[1]};
      f32x2 w1hi = {w1_cur[2], w1_cur[3]};
      #pragma unroll
      for (int k = 0; k < D3; ++k) {
        const float zz = (i == 0) ? zq[k].x : (i == 1) ? zq[k].y
                       : (i == 2) ? zq[k].z : zq[k].w;
        f32x2 zv = {zz, zz};
        acc[0][0][SB + k] = __builtin_elementwise_fma(w0lo, zv, acc[0][0][SB + k]);
        acc[0][1][SB + k] = __builtin_elementwise_fma(w0hi, zv, acc[0][1][SB + k]);
        acc[1][0][SB + k] = __builtin_elementwise_fma(w1lo, zv, acc[1][0][SB + k]);
        acc[1][1][SB + k] = __builtin_elementwise_fma(w1hi, zv, acc[1][1][SB + k]);
      }
      if (g < 7) { w0_cur = w0n; w1_cur = w1n; }
    }
  }
}

// NOTE (journal): VGPR alloc quantizes at 64/128/256 (m68/m69): buckets are
// <=64 -> 8 waves/SIMD (r11: 71.7us barriered), <=128 -> 4 waves (r13: 68.2us),
// <=256 -> 2 waves (r10: 109us). r18's VGPR-92 two-pass proved 92 rounds to the
// 128 bucket (occupancy unchanged, z-dup cost -> 73.1us). Surface fully mapped;
// r13 is the minimum. r19: final restore of r13 (reproduced 68.2/68.3 in r13/r17).
__global__ __launch_bounds__(BLOCK, 2) void conv_kernel(
    const float* __restrict__ xg, const float* __restrict__ shg,
    const float* __restrict__ dist, const float* __restrict__ freq,
    const float* __restrict__ W1, const float* __restrict__ b1,
    const unsigned short* __restrict__ W2b,
    float* __restrict__ out)
{
  __shared__ float s_pool[POOLSZ];        // 30464 B
  float* s_sh = s_pool + OFF_SH;

  const int tid = threadIdx.x;
  const int e0 = blockIdx.x * EPB;
  const int lane = tid & 63;
  const int ls = lane & 15;       // e-col (B/C cols) & w-row selector (A rows)
  const int lq = lane >> 4;       // 0..3 k-slice / output reg quad
  const int q   = tid >> 6;       // 0..3 u-quarter (wave id)
  float* zw = s_pool + q * ZG_SIZE;                        // private group-z
  float* s_basis = s_pool + 2 * ZG_SIZE;                   // alias wave-2 z
  unsigned short* s_hb = (unsigned short*)(s_pool + 3 * ZG_SIZE); // alias wave-3 z

  // ---- prologue A: sh + radial basis ----
  if (tid < EPB * DIM_SHD) {
    int e = tid / DIM_SHD, c = tid - (tid / DIM_SHD) * DIM_SHD;
    s_sh[e * 12 + c] = shg[(size_t)(e0 + e) * DIM_SHD + c];
  }
  if (tid < EPB * NB) {
    int e = tid / NB, n = tid - (tid / NB) * NB;
    float d  = dist[e0 + e];
    float xv = d * 0.25f;
    float x2 = xv * xv, x4 = x2 * x2, x5 = x4 * xv;
    float env = 1.0f / xv + x5 * fmaf(xv, fmaf(xv, -21.0f, 48.0f), -28.0f);
    env = (xv < 1.0f) ? env : 0.0f;
    s_basis[e * NB + n] = env * sinf(freq[n] * xv);
  }
  __syncthreads();

  // ---- prologue B: radial MLP hidden layer (256 tasks) ----
  {
    int e = tid >> 4, t = tid & 15;
    float v = b1[t];
    #pragma unroll
    for (int n = 0; n < NB; ++n) v = fmaf(s_basis[e * NB + n], W1[n * NH + t], v);
    v = v / (1.0f + expf(-v));          // silu
    s_hb[e * 32 + t] = f2bf(v);
    s_hb[e * 32 + t + 16] = (t == 0) ? (unsigned short)0x3F80 : (unsigned short)0;
  }
  __syncthreads();
  short8b hB = *(const short8b*)(s_hb + ls * 32 + lq * 8);
  __syncthreads();   // all waves hold hB before waves 2/3 overwrite aliased buffers

  f32x2 acc[2][2][9];
  #pragma unroll
  for (int wt = 0; wt < 2; ++wt)
    #pragma unroll
    for (int p = 0; p < 2; ++p)
      #pragma unroll
      for (int a = 0; a < 9; ++a) acc[wt][p][a] = (f32x2){0.f, 0.f};

  // ---- main loop: wave-independent, zero barriers, grouped ----
  z_group_l0(lane, q, e0, xg, s_sh, zw);
  contract_q< 0, 1, 0, 0>(ls, lq, q, W2b, zw, hB, acc);
  contract_q< 1, 3, 1, 1>(ls, lq, q, W2b, zw, hB, acc);
  contract_q< 2, 5, 4, 4>(ls, lq, q, W2b, zw, hB, acc);

  z_group_l1(lane, q, e0, xg, s_sh, zw);
  contract_q< 3, 3, 1, 0>(ls, lq, q, W2b, zw, hB, acc);
  contract_q< 4, 1, 0, 3>(ls, lq, q, W2b, zw, hB, acc);
  contract_q< 5, 5, 4, 4>(ls, lq, q, W2b, zw, hB, acc);
  contract_q< 6, 3, 1, 9>(ls, lq, q, W2b, zw, hB, acc);

  z_group_l2(lane, q, e0, xg, s_sh, zw);
  contract_q< 7, 5, 4, 0>(ls, lq, q, W2b, zw, hB, acc);
  contract_q< 8, 3, 1, 5>(ls, lq, q, W2b, zw, hB, acc);
  contract_q< 9, 1, 0, 8>(ls, lq, q, W2b, zw, hB, acc);
  contract_q<10, 5, 4, 9>(ls, lq, q, W2b, zw, hB, acc);

  // ---- epilogue: 4-way u-quarter reduction into pool (z dead), store ----
  __syncthreads();
  float* s_og = s_pool;            // stride XSTR=292, 4672 fl <= z region
  #pragma unroll
  for (int ph = 3; ph >= 0; --ph) {
    if (q == ph) {
      float* row = s_og + ls * XSTR;
      #pragma unroll
      for (int wt = 0; wt < 2; ++wt) {
        #pragma unroll
        for (int r = 0; r < 4; ++r) {
          const int w = wt * 16 + lq * 4 + r;
          float vals[9];
          #pragma unroll
          for (int a = 0; a < 9; ++a)
            vals[a] = (r & 1) ? acc[wt][r >> 1][a].y : acc[wt][r >> 1][a].x;
          if (ph == 3) {
            row[w] = vals[0];
            #pragma unroll
            for (int k = 0; k < 3; ++k) row[32 + w * 3 + k] = vals[1 + k];
            #pragma unroll
            for (int k = 0; k < 5; ++k) row[128 + w * 5 + k] = vals[4 + k];
          } else {
            row[w] += vals[0];
            #pragma unroll
            for (int k = 0; k < 3; ++k) row[32 + w * 3 + k] += vals[1 + k];
            #pragma unroll
            for (int k = 0; k < 5; ++k) row[128 + w * 5 + k] += vals[4 + k];
          }
        }
      }
    }
    __syncthreads();
  }
  // coalesced store: 16 rows x 288 = 1152 float4
  for (int i4 = tid; i4 < EPB * 72; i4 += BLOCK) {
    int e = i4 / 72, r = i4 - e * 72;
    float4 v = *(const float4*)(s_og + e * XSTR + r * 4);
    *(float4*)(out + (size_t)(e0 + e) * DIM_IN + r * 4) = v;
  }
}

// ===================== host-side Wigner-3j (mirrors reference) =====================
typedef std::complex<double> cd;

static double factd(int n) { double r = 1; for (int i = 2; i <= n; ++i) r *= i; return r; }

static double su2_cg(int j1, int j2, int j3, int m1, int m2, int m3) {
  if (m3 != m1 + m2) return 0.0;
  int vmin = std::max(std::max(-j1 + j2 + m3, -j1 + m1), 0);
  int vmax = std::min(std::min(j2 + j3 + m1, j3 - j1 + j2), j3 + m3);
  if (vmax < vmin) return 0.0;
  double c = std::sqrt(
      factd(2*j3+1) * factd(j3+j1-j2) * factd(j3-j1+j2) * factd(j1+j2-j3) / factd(j1+j2+j3+1)
      * factd(j3+m3) * factd(j3-m3)
      / (factd(j1+m1) * factd(j1-m1) * factd(j2+m2) * factd(j2-m2)));
  double s = 0.0;
  for (int v = vmin; v <= vmax; ++v) {
    double sg = ((v + j2 + m2) & 1) ? -1.0 : 1.0;
    s += sg * factd(j2+j3+m1-v) * factd(j1-m1+v)
         / (factd(v) * factd(j3-j1+j2-v) * factd(j3+m3-v) * factd(v+j1-j2-m3));
  }
  return c * s;
}

static void qmat(int l, cd q[5][5]) {
  for (int a = 0; a < 5; ++a) for (int b = 0; b < 5; ++b) q[a][b] = cd(0, 0);
  const double s = 1.0 / std::sqrt(2.0);
  for (int m = -l; m < 0; ++m) {
    q[l + m][l - m] = cd(s, 0);
    q[l + m][l + m] = cd(0, -s);
  }
  q[l][l] = cd(1, 0);
  for (int m = 1; m <= l; ++m) {
    double sg = (m & 1) ? -1.0 : 1.0;
    q[l + m][l + m] = cd(sg * s, 0);
    q[l + m][l - m] = cd(0, sg * s);
  }
  cd ph = (l == 0) ? cd(1, 0) : (l == 1) ? cd(0, -1) : cd(-1, 0);  // (-i)^l
  for (int a = 0; a < 5; ++a) for (int b = 0; b < 5; ++b) q[a][b] *= ph;
}

static void wigner3j(int l1, int l2, int l3, double C[5][5][5]) {
  int d1 = 2*l1+1, d2 = 2*l2+1, d3 = 2*l3+1;
  cd q1[5][5], q2[5][5], q3[5][5];
  qmat(l1, q1); qmat(l2, q2); qmat(l3, q3);
  double norm2 = 0;
  for (int j = 0; j < d1; ++j)
    for (int l = 0; l < d2; ++l)
      for (int n = 0; n < d3; ++n) {
        cd sum(0, 0);
        for (int i = 0; i < d1; ++i)
          for (int k = 0; k < d2; ++k)
            for (int m = 0; m < d3; ++m) {
              double cg = su2_cg(l1, l2, l3, i - l1, k - l2, m - l3);
              if (cg != 0.0) sum += q1[i][j] * q2[k][l] * std::conj(q3[m][n]) * cg;
            }
        C[j][l][n] = sum.real();
        norm2 += C[j][l][n] * C[j][l][n];
      }
  double nrm = std::sqrt(norm2);
  if (nrm > 0)
    for (int j = 0; j < d1; ++j)
      for (int l = 0; l < d2; ++l)
        for (int n = 0; n < d3; ++n) C[j][l][n] /= nrm;
}

static void build_C_host(float C_out[NINSTR][125]) {
  const int L1[NINSTR] = {0,0,0,1,1,1,1,2,2,2,2};
  const int L2[NINSTR] = {0,1,2,0,1,1,2,0,1,2,2};
  const int L3[NINSTR] = {0,1,2,1,0,2,1,2,1,0,2};
  std::memset(C_out, 0, sizeof(float) * NINSTR * 125);
  for (int ins = 0; ins < NINSTR; ++ins) {
    int l1 = L1[ins], l2 = L2[ins], l3 = L3[ins];
    int d1 = 2*l1+1, d2 = 2*l2+1, d3 = 2*l3+1;
    double C[5][5][5];
    wigner3j(l1, l2, l3, C);
    double fan = (l3 == 0) ? 96.0 : 128.0;
    double pw = std::sqrt((2*l3+1) / fan);
    for (int i = 0; i < d1; ++i)
      for (int j = 0; j < d2; ++j)
        for (int k = 0; k < d3; ++k)
          C_out[ins][(i * d2 + j) * d3 + k] = (float)(pw * C[i][j][k]);
  }
}

extern "C" void kernel_launch(void* const* d_in, const int* in_sizes, int n_in,
                              void* d_out, int out_size, void* d_ws, size_t ws_size,
                              hipStream_t stream) {
  static float hC[NINSTR][125];
  build_C_host(hC);
  void* dC = nullptr;
  hipGetSymbolAddress(&dC, HIP_SYMBOL(g_C));
  hipMemcpyAsync(dC, hC, sizeof(hC), hipMemcpyHostToDevice, stream);

  const float* xg   = (const float*)d_in[0];
  const float* shg  = (const float*)d_in[1];
  const float* dist = (const float*)d_in[2];
  const float* freq = (const float*)d_in[3];
  const float* W1   = (const float*)d_in[4];
  const float* b1   = (const float*)d_in[5];
  const float* W2   = (const float*)d_in[6];
  const float* b2   = (const float*)d_in[7];
  float* out = (float*)d_out;
  unsigned short* W2b = (unsigned short*)d_ws;    // 720896 bytes

  prep_w2<<<(W2B_ELEMS + 255) / 256, 256, 0, stream>>>(W2, b2, W2b);

  int E = in_sizes[2];            // 16384
  int blocks = E / EPB;           // 1024
  conv_kernel<<<blocks, BLOCK, 0, stream>>>(xg, shg, dist, freq, W1, b1, W2b, out);
}